// Round 4
// baseline (756.098 us; speedup 1.0000x reference)
//
#include <hip/hip_runtime.h>
#include <hip/hip_bf16.h>
#include <math.h>

#define BB 64
#define TT 512
#define IW 256
#define HH 512
#define G3H 1536

__device__ __forceinline__ double dshfl_xor(double v, int m){
  int2 a = *(int2*)&v;
  a.x = __shfl_xor(a.x, m, 64);
  a.y = __shfl_xor(a.y, m, 64);
  return *(double*)&a;
}

__global__ void sentinel_k(float* out, float v){
  out[0] = v;
}

// w_d[h] = sum_j Wl[j][h]
__global__ __launch_bounds__(256) void colsum_d(const float* __restrict__ Wl, double* __restrict__ w_d){
  int h = blockIdx.x*256 + threadIdx.x;
  if (h >= HH) return;
  double acc = 0.0;
  for (int j = 0; j < HH; ++j) acc += (double)Wl[(size_t)j*HH + h];
  w_d[h] = acc;
}

// fused gates + GRU for layer l; h_all[s][b][l][h] (f32)
__global__ __launch_bounds__(256) void gru_fused(const float* __restrict__ x,
    const float* __restrict__ Wih0, const float* __restrict__ bih0, const float* __restrict__ bhh0,
    const float* __restrict__ WihL, const float* __restrict__ bihL, const float* __restrict__ bhhL,
    float* __restrict__ h_all, int l){
  int idx = blockIdx.x*256 + threadIdx.x;   // [0,98304)
  int h = idx & 511;
  int t2 = idx >> 9;
  int b = t2 & 63;
  int s = t2 >> 6;
  double a0=0.0, a1=0.0, a2=0.0;
  const float* bih; const float* bhh;
  if (l == 0){
    const float* xr = x + (size_t)b*TT*IW;                      // x[b][0][:]
    const float* w0 = Wih0 + ((size_t)s*G3H + h)*IW;            // r row
    const float* w1 = Wih0 + ((size_t)s*G3H + 512 + h)*IW;      // z row
    const float* w2 = Wih0 + ((size_t)s*G3H + 1024 + h)*IW;     // n row
    for (int i = 0; i < IW; ++i){
      double xv = (double)xr[i];
      a0 += xv*(double)w0[i]; a1 += xv*(double)w1[i]; a2 += xv*(double)w2[i];
    }
    bih = bih0 + (size_t)s*G3H;
    bhh = bhh0 + (size_t)s*G3H;
  } else {
    const float* hr = h_all + (((size_t)s*BB + b)*3 + (l-1))*HH; // h_all[s][b][l-1][:]
    const float* w0 = WihL + (((size_t)s*2 + (l-1))*G3H + h)*HH; // WihL[s][l-1][h][:]
    const float* w1 = w0 + (size_t)512*HH;
    const float* w2 = w0 + (size_t)1024*HH;
    for (int k = 0; k < HH; ++k){
      double hv = (double)hr[k];
      a0 += hv*(double)w0[k]; a1 += hv*(double)w1[k]; a2 += hv*(double)w2[k];
    }
    bih = bihL + ((size_t)s*2 + (l-1))*G3H;
    bhh = bhhL + ((size_t)s*2 + (l-1))*G3H;
  }
  double gr = a0 + (double)bih[h]        + (double)bhh[h];
  double gz = a1 + (double)bih[512+h]    + (double)bhh[512+h];
  double gn = a2 + (double)bih[1024+h];
  double r = 1.0/(1.0 + exp(-gr));
  double z = 1.0/(1.0 + exp(-gz));
  double n = tanh(gn + r*(double)bhh[1024+h]);
  h_all[(((size_t)s*BB + b)*3 + l)*HH + h] = (float)((1.0 - z)*n);
}

// per (s,b,l): score = h.w ; dmat[c] = h.Ws[c][:512]
__global__ __launch_bounds__(192) void dots_d(const float* __restrict__ h_all,
                                              const double* __restrict__ w_d,
                                              const float* __restrict__ Ws,
                                              double* __restrict__ score_d,
                                              double* __restrict__ dmat_d){
  int idx = blockIdx.x*192 + threadIdx.x;     // [0,576): (s*64+b)*3 + l
  if (idx >= 576) return;
  const float* hp = h_all + (size_t)idx*HH;
  double a0=0.0, a1=0.0, a2=0.0, a3=0.0;
  for (int h = 0; h < HH; ++h){
    double hv = (double)hp[h];
    a0 += hv * w_d[h];
    a1 += hv * (double)Ws[h];
    a2 += hv * (double)Ws[768 + h];
    a3 += hv * (double)Ws[1536 + h];
  }
  score_d[idx] = a0;
  dmat_d[idx*3 + 0] = a1;
  dmat_d[idx*3 + 1] = a2;
  dmat_d[idx*3 + 2] = a3;
}

// P1[s][c][b] = sum_l softmax_l(score)[l]*dmat[l][c] + bs[c]
__global__ __launch_bounds__(192) void fold2_d(const double* __restrict__ score_d,
                                               const double* __restrict__ dmat_d,
                                               const float* __restrict__ bs,
                                               double* __restrict__ P1){
  int tid = threadIdx.x;                      // 192: s*64+b
  int s = tid / 64, b = tid & 63;
  int base = s*192 + b*3;
  double a0 = score_d[base], a1 = score_d[base+1], a2 = score_d[base+2];
  double m = fmax(a0, fmax(a1, a2));
  double e0 = exp(a0-m), e1 = exp(a1-m), e2 = exp(a2-m);
  double inv = 1.0/(e0+e1+e2);
  e0 *= inv; e1 *= inv; e2 *= inv;
  for (int c = 0; c < 3; ++c){
    double v = e0*dmat_d[base*3 + c] + e1*dmat_d[(base+1)*3 + c] + e2*dmat_d[(base+2)*3 + c];
    P1[(s*3 + c)*64 + b] = v + (double)bs[c];
  }
}

// D[t][c][b] = dot(x[b][t][:], Ws[c][512:768])  (f32 store of f64 acc)
__global__ __launch_bounds__(64) void xdot2_d(const float* __restrict__ x,
                                              const float* __restrict__ Ws,
                                              float* __restrict__ D){
  int t = blockIdx.x;
  int b = threadIdx.x;
  const float* xr = x + ((size_t)b*TT + t)*IW;
  double a0=0.0, a1=0.0, a2=0.0;
  for (int i = 0; i < IW; ++i){
    double xv = (double)xr[i];
    a0 += xv * (double)Ws[0*768 + 512 + i];
    a1 += xv * (double)Ws[1*768 + 512 + i];
    a2 += xv * (double)Ws[2*768 + 512 + i];
  }
  D[(t*3 + 0)*64 + b] = (float)a0;
  D[(t*3 + 1)*64 + b] = (float)a1;
  D[(t*3 + 2)*64 + b] = (float)a2;
}

// sequential scan: per-step softmax(P1[cur] + D[t]) in f64, lane = b
__global__ __launch_bounds__(64) void scan2_d(const double* __restrict__ P1,
                                              const float* __restrict__ D,
                                              int* __restrict__ curbuf){
  int lane = threadIdx.x;
  double pc[3][3];
  for (int s = 0; s < 3; ++s)
    for (int c = 0; c < 3; ++c)
      pc[s][c] = P1[(s*3 + c)*64 + lane];
  double q0 = 0.5, q1 = 1.0, q2 = 1.0;
  int cur = 0;
  if (lane == 0) curbuf[0] = 0;
  double d0 = (double)D[1*192 + lane];
  double d1 = (double)D[1*192 + 64 + lane];
  double d2 = (double)D[1*192 + 128 + lane];
  for (int t = 1; t < TT; ++t){
    double n0 = 0.0, n1 = 0.0, n2 = 0.0;
    if (t + 1 < TT){
      const float* Dn = D + (size_t)(t+1)*192;
      n0 = (double)Dn[lane]; n1 = (double)Dn[64+lane]; n2 = (double)Dn[128+lane];
    }
    double l0 = pc[cur][0] + d0;
    double l1 = pc[cur][1] + d1;
    double l2 = pc[cur][2] + d2;
    double m = fmax(l0, fmax(l1, l2));
    double e0 = exp(l0 - m), e1 = exp(l1 - m), e2 = exp(l2 - m);
    double inv = 1.0/(e0 + e1 + e2);
    e0 *= inv; e1 *= inv; e2 *= inv;
    for (int mm = 32; mm; mm >>= 1){
      e0 += dshfl_xor(e0, mm);
      e1 += dshfl_xor(e1, mm);
      e2 += dshfl_xor(e2, mm);
    }
    double s0 = q0*e0, s1 = q1*e1, s2 = q2*e2;
    int c = 0; double best = s0;
    if (s1 > best){ best = s1; c = 1; }
    if (s2 > best){ best = s2; c = 2; }
    cur = c;
    if (c == 0) q0 *= 0.5; else if (c == 1) q1 *= 0.5; else q2 *= 0.5;
    double qm = fmax(q0, fmax(q1, q2));
    q0 /= qm; q1 /= qm; q2 /= qm;
    if (lane == 0) curbuf[t] = c;
    d0 = n0; d1 = n1; d2 = n2;
  }
}

// outputs: f32 copies
__global__ __launch_bounds__(256) void out_main(const float* __restrict__ h_all,
                                                const int* __restrict__ curbuf,
                                                float* __restrict__ out){
  int t = blockIdx.x;
  int cur = curbuf[t];
  const float* base = h_all + (((size_t)cur*BB)*3 + 2)*HH;  // [cur][b][2][:], b-stride 1536
  int tid = threadIdx.x;
  for (int k = 0; k < 32; ++k){
    int e4 = (k*256 + tid)*4;                               // [0, 32768)
    int b = e4 >> 9, h = e4 & 511;
    float4 v = *(const float4*)(base + (size_t)b*1536 + h);
    *(float4*)(&out[((size_t)b*TT + t)*HH + h]) = v;
  }
}

__global__ __launch_bounds__(256) void out_fin(const float* __restrict__ h_all,
                                               const int* __restrict__ curbuf,
                                               float* __restrict__ out){
  int cur = curbuf[TT-1];
  int e4 = (blockIdx.x*256 + threadIdx.x)*4;                // [0, 98304)
  float4 v = *(const float4*)(h_all + (size_t)cur*98304 + e4);
  *(float4*)(&out[(size_t)BB*TT*HH + e4]) = v;
}

extern "C" void kernel_launch(void* const* d_in, const int* in_sizes, int n_in,
                              void* d_out, int out_size, void* d_ws, size_t ws_size,
                              hipStream_t stream){
  const float* x    = (const float*)d_in[0];
  const float* Wl   = (const float*)d_in[1];
  // d_in[2] = bl : constant over L inside softmax -> cancels; unused
  const float* Ws   = (const float*)d_in[3];
  const float* bs   = (const float*)d_in[4];
  const float* Wih0 = (const float*)d_in[5];
  const float* bih0 = (const float*)d_in[6];
  const float* bhh0 = (const float*)d_in[7];
  const float* WihL = (const float*)d_in[8];
  const float* bihL = (const float*)d_in[9];
  const float* bhhL = (const float*)d_in[10];
  float* out = (float*)d_out;

  // ---- sanity sentinels (f32 now) ----
  static const int exp_sizes[11] = {8388608, 262144, 512, 2304, 3,
                                    1179648, 4608, 4608, 4718592, 9216, 9216};
  int bad = 0;
  if (n_in != 11) bad = 13;
  else {
    for (int i = 0; i < 11; ++i) if (in_sizes[i] != exp_sizes[i]) { bad = i + 1; break; }
  }
  if (!bad && out_size != 16875520) bad = 12;
  if (bad){
    sentinel_k<<<dim3(1), dim3(1), 0, stream>>>(out, 1048576.0f * (float)bad);
    return;
  }
  if (ws_size < 1602048){
    sentinel_k<<<dim3(1), dim3(1), 0, stream>>>(out, 3.0e7f + (float)(ws_size >> 6));
    return;
  }

  // ---- ws layout (1,602,048 B) ----
  double* w_d     = (double*)d_ws;              // 512
  double* score_d = w_d + 512;                  // 576
  double* dmat_d  = score_d + 576;              // 1728
  double* P1      = dmat_d + 1728;              // 576
  float*  h_all   = (float*)(P1 + 576);         // 294912 f32
  float*  D       = h_all + 294912;             // 98304 f32
  int*    curbuf  = (int*)(D + 98304);          // 512 ints

  colsum_d<<<dim3(2), dim3(256), 0, stream>>>(Wl, w_d);
  xdot2_d <<<dim3(512), dim3(64), 0, stream>>>(x, Ws, D);

  for (int l = 0; l < 3; ++l)
    gru_fused<<<dim3(384), dim3(256), 0, stream>>>(x, Wih0, bih0, bhh0,
                                                   WihL, bihL, bhhL, h_all, l);

  dots_d <<<dim3(3), dim3(192), 0, stream>>>(h_all, w_d, Ws, score_d, dmat_d);
  fold2_d<<<dim3(1), dim3(192), 0, stream>>>(score_d, dmat_d, bs, P1);

  scan2_d<<<dim3(1), dim3(64), 0, stream>>>(P1, D, curbuf);

  out_main<<<dim3(512), dim3(256), 0, stream>>>(h_all, curbuf, out);
  out_fin <<<dim3(96),  dim3(256), 0, stream>>>(h_all, curbuf, out);
}

// Round 5
// 280.084 us; speedup vs baseline: 2.6995x; 2.6995x over previous
//
#include <hip/hip_runtime.h>
#include <hip/hip_bf16.h>
#include <math.h>

#define BB 64
#define TT 512
#define IW 256
#define HH 512
#define G3H 1536

__device__ __forceinline__ double dshfl_xor(double v, int m){
  int2 a = *(int2*)&v;
  a.x = __shfl_xor(a.x, m, 64);
  a.y = __shfl_xor(a.y, m, 64);
  return *(double*)&a;
}

__global__ void sentinel_k(float* out, float v){ out[0] = v; }

// ---------------- precompute ----------------

__global__ __launch_bounds__(256) void transpose_x0(const float* __restrict__ x, float* __restrict__ x0T){
  int idx = blockIdx.x*256 + threadIdx.x;          // [0, 16384)
  int b = idx >> 8, i = idx & 255;
  x0T[i*64 + b] = x[(size_t)b*TT*IW + i];          // x[b][0][i]
}

// w_d[h] = sum_j Wl[j][h]  (f64 partials)
__global__ __launch_bounds__(256) void colsum8(const float* __restrict__ Wl, double* __restrict__ w_d){
  __shared__ double part[4][64];
  int lane = threadIdx.x & 63, ty = threadIdx.x >> 6;
  int h = blockIdx.x*64 + lane;
  double acc = 0.0;
  for (int j = ty*128; j < ty*128 + 128; ++j) acc += (double)Wl[(size_t)j*HH + h];
  part[ty][lane] = acc;
  __syncthreads();
  if (ty == 0) w_d[h] = part[0][lane] + part[1][lane] + part[2][lane] + part[3][lane];
}

// gi[s][g][b] = sum_k W[s][g][k] * xT[s][k][b] + bih[s][g]   (f32)
template<int K>
__global__ __launch_bounds__(64) void gemm_gates(const float* __restrict__ W, long wStrideS,
                                                 const float* __restrict__ bih, int bStrideS,
                                                 const float* __restrict__ xT, int xStrideS,
                                                 float* __restrict__ gi){
  __shared__ float wlds[4][K];
  int lane = threadIdx.x;
  int s  = blockIdx.x / 384;
  int g0 = (blockIdx.x % 384) * 4;
  const float* Wp = W + (size_t)s*wStrideS + (size_t)g0*K;
  for (int j = 0; j < 4; ++j)
    for (int i = lane; i < K; i += 64) wlds[j][i] = Wp[(size_t)j*K + i];
  __syncthreads();
  const float* xp = xT + (size_t)s*xStrideS + lane;
  float a0=0.f, a1=0.f, a2=0.f, a3=0.f;
  #pragma unroll 8
  for (int h = 0; h < K; ++h){
    float xv = xp[(size_t)h*64];
    a0 += wlds[0][h]*xv; a1 += wlds[1][h]*xv;
    a2 += wlds[2][h]*xv; a3 += wlds[3][h]*xv;
  }
  const float* bp = bih + (size_t)s*bStrideS + g0;
  float* gp = gi + ((size_t)(s*G3H + g0))*64 + lane;
  gp[0]   = a0 + bp[0];
  gp[64]  = a1 + bp[1];
  gp[128] = a2 + bp[2];
  gp[192] = a3 + bp[3];
}

// GRU activation (f32); bhh pre-offset to layer, sStride in elements
__global__ __launch_bounds__(256) void gru_f(const float* __restrict__ gi,
                                             const float* __restrict__ bhh, int sStride,
                                             float* __restrict__ h_all, float* __restrict__ hT, int l){
  int idx = blockIdx.x*256 + threadIdx.x;          // [0, 98304)
  int b = idx & 63;
  int h = (idx >> 6) & 511;
  int s = idx >> 15;
  float gr = gi[((size_t)(s*G3H        + h))*64 + b];
  float gz = gi[((size_t)(s*G3H + 512  + h))*64 + b];
  float gn = gi[((size_t)(s*G3H + 1024 + h))*64 + b];
  const float* bp = bhh + (size_t)s*sStride;
  float r = 1.f/(1.f + expf(-(gr + bp[h])));
  float z = 1.f/(1.f + expf(-(gz + bp[512 + h])));
  float n = tanhf(gn + r*bp[1024 + h]);
  float hv = (1.f - z)*n;
  h_all[(((size_t)s*BB + b)*3 + l)*HH + h] = hv;
  hT[((size_t)s*HH + h)*BB + b] = hv;
}

// per (s,b,l): score = h.w ; dmat[c] = h.Ws[c][:512]   (f64 acc over f32 h)
__global__ __launch_bounds__(192) void dots_d(const float* __restrict__ h_all,
                                              const double* __restrict__ w_d,
                                              const float* __restrict__ Ws,
                                              double* __restrict__ score_d,
                                              double* __restrict__ dmat_d){
  int idx = blockIdx.x*192 + threadIdx.x;          // [0,576): (s*64+b)*3 + l
  if (idx >= 576) return;
  const float* hp = h_all + (size_t)idx*HH;
  double a0=0.0, a1=0.0, a2=0.0, a3=0.0;
  for (int h = 0; h < HH; ++h){
    double hv = (double)hp[h];
    a0 += hv * w_d[h];
    a1 += hv * (double)Ws[h];
    a2 += hv * (double)Ws[768 + h];
    a3 += hv * (double)Ws[1536 + h];
  }
  score_d[idx] = a0;
  dmat_d[idx*3 + 0] = a1;
  dmat_d[idx*3 + 1] = a2;
  dmat_d[idx*3 + 2] = a3;
}

// P1[s][c][b] = sum_l softmax_l(score)[l]*dmat[l][c] + bs[c]
__global__ __launch_bounds__(192) void fold2_d(const double* __restrict__ score_d,
                                               const double* __restrict__ dmat_d,
                                               const float* __restrict__ bs,
                                               double* __restrict__ P1){
  int tid = threadIdx.x;                           // 192: s*64+b
  int s = tid / 64, b = tid & 63;
  int base = s*192 + b*3;
  double a0 = score_d[base], a1 = score_d[base+1], a2 = score_d[base+2];
  double m = fmax(a0, fmax(a1, a2));
  double e0 = exp(a0-m), e1 = exp(a1-m), e2 = exp(a2-m);
  double inv = 1.0/(e0+e1+e2);
  e0 *= inv; e1 *= inv; e2 *= inv;
  for (int c = 0; c < 3; ++c){
    double v = e0*dmat_d[base*3 + c] + e1*dmat_d[(base+1)*3 + c] + e2*dmat_d[(base+2)*3 + c];
    P1[(s*3 + c)*64 + b] = v + (double)bs[c];
  }
}

// D[t][c][b] = dot(x[b][t][:], Ws[c][512:768])  (float4 loads, f64 acc)
__global__ __launch_bounds__(64) void xdot_f(const float* __restrict__ x,
                                             const float* __restrict__ Ws,
                                             float* __restrict__ D){
  __shared__ float wl[3][IW];
  int t = blockIdx.x, lane = threadIdx.x;
  for (int c = 0; c < 3; ++c)
    for (int i = lane; i < IW; i += 64) wl[c][i] = Ws[c*768 + 512 + i];
  __syncthreads();
  const float4* xr = (const float4*)(x + ((size_t)lane*TT + t)*IW);
  double a0=0.0, a1=0.0, a2=0.0;
  #pragma unroll 8
  for (int i4 = 0; i4 < 64; ++i4){
    float4 xv = xr[i4];
    int i = i4*4;
    a0 += (double)xv.x*wl[0][i] + (double)xv.y*wl[0][i+1] + (double)xv.z*wl[0][i+2] + (double)xv.w*wl[0][i+3];
    a1 += (double)xv.x*wl[1][i] + (double)xv.y*wl[1][i+1] + (double)xv.z*wl[1][i+2] + (double)xv.w*wl[1][i+3];
    a2 += (double)xv.x*wl[2][i] + (double)xv.y*wl[2][i+1] + (double)xv.z*wl[2][i+2] + (double)xv.w*wl[2][i+3];
  }
  D[((size_t)t*3 + 0)*64 + lane] = (float)a0;
  D[((size_t)t*3 + 1)*64 + lane] = (float)a1;
  D[((size_t)t*3 + 2)*64 + lane] = (float)a2;
}

// S[t][cur][c] = sum_b softmax_c(P1[cur]+D[t])[b]  — parallel over (t, cur)
__global__ __launch_bounds__(192) void sums_k(const double* __restrict__ P1,
                                              const float* __restrict__ D,
                                              double* __restrict__ Ssum){
  int t = blockIdx.x;
  int cu = threadIdx.x >> 6;
  int lane = threadIdx.x & 63;
  double l0 = P1[(cu*3+0)*64+lane] + (double)D[((size_t)t*3+0)*64+lane];
  double l1 = P1[(cu*3+1)*64+lane] + (double)D[((size_t)t*3+1)*64+lane];
  double l2 = P1[(cu*3+2)*64+lane] + (double)D[((size_t)t*3+2)*64+lane];
  double m = fmax(l0, fmax(l1, l2));
  double e0 = exp(l0-m), e1 = exp(l1-m), e2 = exp(l2-m);
  double inv = 1.0/(e0+e1+e2);
  e0 *= inv; e1 *= inv; e2 *= inv;
  for (int mm = 32; mm; mm >>= 1){
    e0 += dshfl_xor(e0, mm); e1 += dshfl_xor(e1, mm); e2 += dshfl_xor(e2, mm);
  }
  if (lane == 0){
    double* p = Ssum + ((size_t)t*3 + cu)*3;
    p[0] = e0; p[1] = e1; p[2] = e2;
  }
}

// scalar scan over precomputed sums; penalties are exact powers of two
#define LOAD9(P, R0,R1,R2,R3,R4,R5,R6,R7,R8) { const double* _p = (P); \
  R0=_p[0]; R1=_p[1]; R2=_p[2]; R3=_p[3]; R4=_p[4]; R5=_p[5]; R6=_p[6]; R7=_p[7]; R8=_p[8]; }

#define STEP9(R0,R1,R2,R3,R4,R5,R6,R7,R8, tt) {                         \
  double s0 = (cur==0)?R0:((cur==1)?R3:R6);                             \
  double s1 = (cur==0)?R1:((cur==1)?R4:R7);                             \
  double s2 = (cur==0)?R2:((cur==1)?R5:R8);                             \
  double v0 = q0*s0, v1 = q1*s1, v2 = q2*s2;                            \
  int c = 0; double best = v0;                                          \
  if (v1 > best){ best = v1; c = 1; }                                   \
  if (v2 > best){ best = v2; c = 2; }                                   \
  cur = c;                                                              \
  if (c==0) q0 *= 0.5; else if (c==1) q1 *= 0.5; else q2 *= 0.5;        \
  double qm = fmax(q0, fmax(q1, q2));                                   \
  double sc = (qm < 1.0) ? 2.0 : 1.0;                                   \
  q0 *= sc; q1 *= sc; q2 *= sc;                                         \
  if (lane == 0) curbuf[tt] = c; }

__global__ __launch_bounds__(64) void scan3_d(const double* __restrict__ Ssum,
                                              int* __restrict__ curbuf){
  __shared__ double lds[TT*9];
  int lane = threadIdx.x;
  for (int i = lane; i < TT*9; i += 64) lds[i] = Ssum[i];
  __syncthreads();
  double q0 = 0.5, q1 = 1.0, q2 = 1.0;
  int cur = 0;
  if (lane == 0) curbuf[0] = 0;
  double a0,a1,a2,a3,a4,a5,a6,a7,a8;
  double b0,b1,b2,b3,b4,b5,b6,b7,b8;
  b0=b1=b2=b3=b4=b5=b6=b7=b8=0.0;
  LOAD9(&lds[9], a0,a1,a2,a3,a4,a5,a6,a7,a8);
  for (int t = 1; t < TT; t += 2){
    if (t + 1 < TT) LOAD9(&lds[(t+1)*9], b0,b1,b2,b3,b4,b5,b6,b7,b8);
    STEP9(a0,a1,a2,a3,a4,a5,a6,a7,a8, t);
    if (t + 1 < TT){
      if (t + 2 < TT) LOAD9(&lds[(t+2)*9], a0,a1,a2,a3,a4,a5,a6,a7,a8);
      STEP9(b0,b1,b2,b3,b4,b5,b6,b7,b8, t+1);
    }
  }
}

// ---------------- outputs (f32) ----------------
__global__ __launch_bounds__(256) void out_main(const float* __restrict__ h_all,
                                                const int* __restrict__ curbuf,
                                                float* __restrict__ out){
  int t = blockIdx.x;
  int cur = curbuf[t];
  const float* base = h_all + (size_t)cur*98304 + 2*HH;    // [cur][b][2][:], b-stride 1536
  int tid = threadIdx.x;
  for (int k = 0; k < 32; ++k){
    int e4 = (k*256 + tid)*4;                              // [0, 32768)
    int b = e4 >> 9, h = e4 & 511;
    float4 v = *(const float4*)(base + (size_t)b*1536 + h);
    *(float4*)(&out[((size_t)b*TT + t)*HH + h]) = v;
  }
}

__global__ __launch_bounds__(256) void out_fin(const float* __restrict__ h_all,
                                               const int* __restrict__ curbuf,
                                               float* __restrict__ out){
  int cur = curbuf[TT-1];
  int e4 = (blockIdx.x*256 + threadIdx.x)*4;               // [0, 98304)
  float4 v = *(const float4*)(h_all + (size_t)cur*98304 + e4);
  *(float4*)(&out[(size_t)BB*TT*HH + e4]) = v;
}

extern "C" void kernel_launch(void* const* d_in, const int* in_sizes, int n_in,
                              void* d_out, int out_size, void* d_ws, size_t ws_size,
                              hipStream_t stream){
  const float* x    = (const float*)d_in[0];
  const float* Wl   = (const float*)d_in[1];
  // d_in[2] = bl : constant over L inside softmax -> cancels; unused
  const float* Ws   = (const float*)d_in[3];
  const float* bs   = (const float*)d_in[4];
  const float* Wih0 = (const float*)d_in[5];
  const float* bih0 = (const float*)d_in[6];
  const float* bhh0 = (const float*)d_in[7];
  const float* WihL = (const float*)d_in[8];
  const float* bihL = (const float*)d_in[9];
  const float* bhhL = (const float*)d_in[10];
  float* out = (float*)d_out;

  // ---- sentinels ----
  static const int exp_sizes[11] = {8388608, 262144, 512, 2304, 3,
                                    1179648, 4608, 4608, 4718592, 9216, 9216};
  int bad = 0;
  if (n_in != 11) bad = 13;
  else {
    for (int i = 0; i < 11; ++i) if (in_sizes[i] != exp_sizes[i]) { bad = i + 1; break; }
  }
  if (!bad && out_size != 16875520) bad = 12;
  if (bad){
    sentinel_k<<<dim3(1), dim3(1), 0, stream>>>(out, 1048576.0f * (float)bad);
    return;
  }
  if (ws_size < 1311232){
    sentinel_k<<<dim3(1), dim3(1), 0, stream>>>(out, 3.0e7f + (float)(ws_size >> 6));
    return;
  }

  // ---- ws layout (1,311,232 B) ----
  double* w_d     = (double*)d_ws;              // 512
  double* score_d = w_d + 512;                  // 576
  double* dmat_d  = score_d + 576;              // 1728
  double* P1      = dmat_d + 1728;              // 576
  double* Ssum    = P1 + 576;                   // 4608
  float*  h_all   = (float*)(Ssum + 4608);      // 294912 f32
  float*  x0T     = h_all + 294912;             // 16384 f32
  int*    curbuf  = (int*)(x0T + 16384);        // 512 ints

  // ---- big scratch in d_out tail (dead before out kernels write) ----
  char* outb = (char*)d_out;
  float* gi  = (float*)(outb + 50331648);       // [3][1536][64] f32 = 1,179,648 B
  float* hT  = gi + 294912;                     // [3][512][64]  f32 =   393,216 B
  float* D   = hT + 98304;                      // [512][3][64]  f32 =   393,216 B

  transpose_x0<<<dim3(64), dim3(256), 0, stream>>>(x, x0T);
  colsum8    <<<dim3(8),  dim3(256), 0, stream>>>(Wl, w_d);
  xdot_f     <<<dim3(512), dim3(64), 0, stream>>>(x, Ws, D);

  // GRU stack (f32)
  gemm_gates<256><<<dim3(1152), dim3(64), 0, stream>>>(Wih0, (long)G3H*IW, bih0, G3H, x0T, 0, gi);
  gru_f<<<dim3(384), dim3(256), 0, stream>>>(gi, bhh0, G3H, h_all, hT, 0);
  gemm_gates<512><<<dim3(1152), dim3(64), 0, stream>>>(WihL, (long)2*G3H*HH, bihL, 2*G3H, hT, HH*BB, gi);
  gru_f<<<dim3(384), dim3(256), 0, stream>>>(gi, bhhL, 2*G3H, h_all, hT, 1);
  gemm_gates<512><<<dim3(1152), dim3(64), 0, stream>>>(WihL + (size_t)G3H*HH, (long)2*G3H*HH, bihL + G3H, 2*G3H, hT, HH*BB, gi);
  gru_f<<<dim3(384), dim3(256), 0, stream>>>(gi, bhhL + G3H, 2*G3H, h_all, hT, 2);

  dots_d <<<dim3(3),   dim3(192), 0, stream>>>(h_all, w_d, Ws, score_d, dmat_d);
  fold2_d<<<dim3(1),   dim3(192), 0, stream>>>(score_d, dmat_d, bs, P1);
  sums_k <<<dim3(512), dim3(192), 0, stream>>>(P1, D, Ssum);

  scan3_d<<<dim3(1), dim3(64), 0, stream>>>(Ssum, curbuf);

  out_main<<<dim3(512), dim3(256), 0, stream>>>(h_all, curbuf, out);
  out_fin <<<dim3(96),  dim3(256), 0, stream>>>(h_all, curbuf, out);
}

// Round 6
// 207.085 us; speedup vs baseline: 3.6512x; 1.3525x over previous
//
#include <hip/hip_runtime.h>
#include <hip/hip_bf16.h>
#include <math.h>

#define BB 64
#define TT 512
#define IW 256
#define HH 512
#define G3H 1536

__device__ __forceinline__ double dshfl_xor(double v, int m){
  int2 a = *(int2*)&v;
  a.x = __shfl_xor(a.x, m, 64);
  a.y = __shfl_xor(a.y, m, 64);
  return *(double*)&a;
}

__global__ void sentinel_k(float* out, float v){ out[0] = v; }

// ---------- prep: transpose x0 (blocks 0..63) + colsum Wl (blocks 64..71) ----------
__global__ __launch_bounds__(256) void prep(const float* __restrict__ x, float* __restrict__ x0T,
                                            const float* __restrict__ Wl, double* __restrict__ w_d){
  if (blockIdx.x < 64){
    int idx = blockIdx.x*256 + threadIdx.x;          // [0, 16384)
    int b = idx >> 8, i = idx & 255;
    x0T[i*64 + b] = x[(size_t)b*TT*IW + i];          // x[b][0][i]
  } else {
    __shared__ double part[4][64];
    int lane = threadIdx.x & 63, ty = threadIdx.x >> 6;
    int h = (blockIdx.x - 64)*64 + lane;
    double acc = 0.0;
    for (int j = ty*128; j < ty*128 + 128; ++j) acc += (double)Wl[(size_t)j*HH + h];
    part[ty][lane] = acc;
    __syncthreads();
    if (ty == 0) w_d[h] = part[0][lane] + part[1][lane] + part[2][lane] + part[3][lane];
  }
}

// ---------- gates GEMM: 256 threads, 16 rows/block ----------
// gi[s][g][b] = sum_k W[s][g][k] * xT[s][k][b] + bih[s][g]
template<int K>
__global__ __launch_bounds__(256) void gemm_gates(const float* __restrict__ W, long wStrideS,
                                                  const float* __restrict__ bih, int bStrideS,
                                                  const float* __restrict__ xT, int xStrideS,
                                                  float* __restrict__ gi){
  __shared__ float wlds[16][K];
  int tid = threadIdx.x;
  int lane = tid & 63, w = tid >> 6;
  int s  = blockIdx.x / 96;
  int g0 = (blockIdx.x % 96) * 16;
  const float* Wp = W + (size_t)s*wStrideS + (size_t)g0*K;
  for (int j = 0; j < 16; ++j)
    for (int i = tid; i < K; i += 256) wlds[j][i] = Wp[(size_t)j*K + i];
  __syncthreads();
  const float* xp = xT + (size_t)s*xStrideS + lane;
  int j0 = w*4;
  float a0=0.f, a1=0.f, a2=0.f, a3=0.f;
  #pragma unroll 8
  for (int h = 0; h < K; ++h){
    float xv = xp[(size_t)h*64];
    a0 += wlds[j0  ][h]*xv; a1 += wlds[j0+1][h]*xv;
    a2 += wlds[j0+2][h]*xv; a3 += wlds[j0+3][h]*xv;
  }
  int g = g0 + j0;
  const float* bp = bih + (size_t)s*bStrideS + g;
  float* gp = gi + ((size_t)(s*G3H + g))*64 + lane;
  gp[0]   = a0 + bp[0];
  gp[64]  = a1 + bp[1];
  gp[128] = a2 + bp[2];
  gp[192] = a3 + bp[3];
}

// ---------- GRU activation (f32) ----------
__global__ __launch_bounds__(256) void gru_f(const float* __restrict__ gi,
                                             const float* __restrict__ bhh, int sStride,
                                             float* __restrict__ h_all, float* __restrict__ hT, int l){
  int idx = blockIdx.x*256 + threadIdx.x;          // [0, 98304)
  int b = idx & 63;
  int h = (idx >> 6) & 511;
  int s = idx >> 15;
  float gr = gi[((size_t)(s*G3H        + h))*64 + b];
  float gz = gi[((size_t)(s*G3H + 512  + h))*64 + b];
  float gn = gi[((size_t)(s*G3H + 1024 + h))*64 + b];
  const float* bp = bhh + (size_t)s*sStride;
  float r = 1.f/(1.f + expf(-(gr + bp[h])));
  float z = 1.f/(1.f + expf(-(gz + bp[512 + h])));
  float n = tanhf(gn + r*bp[1024 + h]);
  float hv = (1.f - z)*n;
  h_all[(((size_t)s*BB + b)*3 + l)*HH + h] = hv;
  hT[((size_t)s*HH + h)*BB + b] = hv;
}

// ---------- dots + fold fused: block s (3 blocks, 192 threads) ----------
__global__ __launch_bounds__(192) void dots_fold(const float* __restrict__ h_all,
                                                 const double* __restrict__ w_d,
                                                 const float* __restrict__ Ws,
                                                 const float* __restrict__ bs,
                                                 double* __restrict__ P1){
  __shared__ double scoreL[192];
  __shared__ double dmatL[192][3];
  int s = blockIdx.x, q = threadIdx.x;             // q = b*3 + l
  const float* hp = h_all + ((size_t)s*192 + q)*HH;
  double a0=0.0, a1=0.0, a2=0.0, a3=0.0;
  for (int h = 0; h < HH; ++h){
    double hv = (double)hp[h];
    a0 += hv * w_d[h];
    a1 += hv * (double)Ws[h];
    a2 += hv * (double)Ws[768 + h];
    a3 += hv * (double)Ws[1536 + h];
  }
  scoreL[q] = a0; dmatL[q][0] = a1; dmatL[q][1] = a2; dmatL[q][2] = a3;
  __syncthreads();
  int b = q & 63, c = q >> 6;
  int base = b*3;
  double s0 = scoreL[base], s1 = scoreL[base+1], s2 = scoreL[base+2];
  double m = fmax(s0, fmax(s1, s2));
  double e0 = exp(s0-m), e1 = exp(s1-m), e2 = exp(s2-m);
  double inv = 1.0/(e0+e1+e2);
  e0 *= inv; e1 *= inv; e2 *= inv;
  double v = e0*dmatL[base][c] + e1*dmatL[base+1][c] + e2*dmatL[base+2][c];
  P1[(s*3 + c)*64 + b] = v + (double)bs[c];
}

// ---------- fused xdot + softmax-sums: block t, 192 threads ----------
// Lmat[t][cur*3+c] = log2( sum_b softmax_c(P1[cur]+D[t])[b] ), stride 12
__global__ __launch_bounds__(192) void sums_x(const float* __restrict__ x,
                                              const float* __restrict__ Ws,
                                              const double* __restrict__ P1,
                                              float* __restrict__ Lmat){
  __shared__ float xl[64*257];
  __shared__ float wsl[3*256];
  __shared__ double dl[3*64];
  int t = blockIdx.x, tid = threadIdx.x;
  int lane = tid & 63, w = tid >> 6;               // w = c (phase1) / cur (phase2)
  for (int i = tid; i < 768; i += 192) wsl[i] = Ws[(i >> 8)*768 + 512 + (i & 255)];
  for (int q = tid; q < 4096; q += 192){           // stage x[:,t,:] via float4
    int r = q >> 6, i4 = q & 63;
    float4 v = *(const float4*)(x + ((size_t)r*TT + t)*IW + i4*4);
    float* dst = &xl[r*257 + i4*4];
    dst[0]=v.x; dst[1]=v.y; dst[2]=v.z; dst[3]=v.w;
  }
  __syncthreads();
  {
    const float* xr = &xl[lane*257];
    const float* wr = &wsl[w*256];
    double acc = 0.0;
    #pragma unroll 8
    for (int i = 0; i < 256; ++i) acc += (double)xr[i] * (double)wr[i];
    dl[w*64 + lane] = acc;
  }
  __syncthreads();
  double l0 = P1[(w*3+0)*64 + lane] + dl[0*64 + lane];
  double l1 = P1[(w*3+1)*64 + lane] + dl[1*64 + lane];
  double l2 = P1[(w*3+2)*64 + lane] + dl[2*64 + lane];
  double m = fmax(l0, fmax(l1, l2));
  double e0 = exp(l0-m), e1 = exp(l1-m), e2 = exp(l2-m);
  double inv = 1.0/(e0+e1+e2);
  e0 *= inv; e1 *= inv; e2 *= inv;
  for (int mm = 32; mm; mm >>= 1){
    e0 += dshfl_xor(e0, mm); e1 += dshfl_xor(e1, mm); e2 += dshfl_xor(e2, mm);
  }
  if (lane == 0){
    float* p = Lmat + (size_t)t*12 + w*3;
    p[0] = log2f((float)e0); p[1] = log2f((float)e1); p[2] = log2f((float)e2);
  }
}

// ---------- scalar log-domain scan, 4-deep LDS prefetch ----------
#define LOADQ(X0,X1,X2, tt) { int _t = (tt) < 511 ? (tt) : 511;            \
  const float4* _p = (const float4*)&lds[_t*12]; X0=_p[0]; X1=_p[1]; X2=_p[2]; }

#define STEPQ(X0,X1,X2, tt) {                                              \
  float L0 = (cur==0) ? X0.x : ((cur==1) ? X0.w : X1.z);                   \
  float L1 = (cur==0) ? X0.y : ((cur==1) ? X1.x : X1.w);                   \
  float L2 = (cur==0) ? X0.z : ((cur==1) ? X1.y : X2.x);                   \
  float v0 = L0 - a0, v1 = L1 - a1, v2 = L2 - a2;                          \
  int c = 0; float best = v0;                                              \
  if (v1 > best){ best = v1; c = 1; }                                      \
  if (v2 > best){ c = 2; }                                                 \
  cur = c;                                                                 \
  a0 += (c==0) ? 1.f : 0.f;                                                \
  a1 += (c==1) ? 1.f : 0.f;                                                \
  a2 += (c==2) ? 1.f : 0.f;                                                \
  float mn = fminf(a0, fminf(a1, a2));                                     \
  a0 -= mn; a1 -= mn; a2 -= mn;                                            \
  if (lane == 0) curbuf[tt] = c; }

__global__ __launch_bounds__(64) void scan4(const float* __restrict__ Lmat,
                                            int* __restrict__ curbuf){
  __shared__ float lds[TT*12];
  int lane = threadIdx.x;
  for (int i = lane*4; i < TT*12; i += 256)
    *(float4*)&lds[i] = *(const float4*)&Lmat[i];
  __syncthreads();
  float a0 = 1.f, a1 = 0.f, a2 = 0.f;    // pen = [0.5,1,1] -> exponents [1,0,0]
  int cur = 0;
  if (lane == 0) curbuf[0] = 0;
  float4 A0,A1,A2, B0,B1,B2, C0,C1,C2, D0,D1,D2;
  LOADQ(A0,A1,A2, 1); LOADQ(B0,B1,B2, 2); LOADQ(C0,C1,C2, 3); LOADQ(D0,D1,D2, 4);
  int t = 1;
  for (; t + 3 <= 508; t += 4){
    STEPQ(A0,A1,A2, t);   LOADQ(A0,A1,A2, t+4);
    STEPQ(B0,B1,B2, t+1); LOADQ(B0,B1,B2, t+5);
    STEPQ(C0,C1,C2, t+2); LOADQ(C0,C1,C2, t+6);
    STEPQ(D0,D1,D2, t+3); LOADQ(D0,D1,D2, t+7);
  }
  if (t <= 511){ STEPQ(A0,A1,A2, t); } ++t;
  if (t <= 511){ STEPQ(B0,B1,B2, t); } ++t;
  if (t <= 511){ STEPQ(C0,C1,C2, t); } ++t;
  if (t <= 511){ STEPQ(D0,D1,D2, t); } ++t;
}

// ---------- outputs (f32), fused ----------
__global__ __launch_bounds__(256) void out_all(const float* __restrict__ h_all,
                                               const int* __restrict__ curbuf,
                                               float* __restrict__ out){
  int blk = blockIdx.x;
  if (blk < 512){
    int t = blk;
    int cur = curbuf[t];
    const float* base = h_all + (size_t)cur*98304 + 2*HH;  // [cur][b][2][:], b-stride 1536
    int tid = threadIdx.x;
    for (int k = 0; k < 32; ++k){
      int e4 = (k*256 + tid)*4;                            // [0, 32768)
      int b = e4 >> 9, h = e4 & 511;
      float4 v = *(const float4*)(base + (size_t)b*1536 + h);
      *(float4*)(&out[((size_t)b*TT + t)*HH + h]) = v;
    }
  } else {
    int cur = curbuf[TT-1];
    int e4 = ((blk - 512)*256 + threadIdx.x)*4;            // [0, 98304)
    float4 v = *(const float4*)(h_all + (size_t)cur*98304 + e4);
    *(float4*)(&out[(size_t)BB*TT*HH + e4]) = v;
  }
}

extern "C" void kernel_launch(void* const* d_in, const int* in_sizes, int n_in,
                              void* d_out, int out_size, void* d_ws, size_t ws_size,
                              hipStream_t stream){
  const float* x    = (const float*)d_in[0];
  const float* Wl   = (const float*)d_in[1];
  // d_in[2] = bl : constant over L inside softmax -> cancels; unused
  const float* Ws   = (const float*)d_in[3];
  const float* bs   = (const float*)d_in[4];
  const float* Wih0 = (const float*)d_in[5];
  const float* bih0 = (const float*)d_in[6];
  const float* bhh0 = (const float*)d_in[7];
  const float* WihL = (const float*)d_in[8];
  const float* bihL = (const float*)d_in[9];
  const float* bhhL = (const float*)d_in[10];
  float* out = (float*)d_out;

  // ---- sentinels ----
  static const int exp_sizes[11] = {8388608, 262144, 512, 2304, 3,
                                    1179648, 4608, 4608, 4718592, 9216, 9216};
  int bad = 0;
  if (n_in != 11) bad = 13;
  else {
    for (int i = 0; i < 11; ++i) if (in_sizes[i] != exp_sizes[i]) { bad = i + 1; break; }
  }
  if (!bad && out_size != 16875520) bad = 12;
  if (bad){
    sentinel_k<<<dim3(1), dim3(1), 0, stream>>>(out, 1048576.0f * (float)bad);
    return;
  }
  if (ws_size < 1280512){
    sentinel_k<<<dim3(1), dim3(1), 0, stream>>>(out, 3.0e7f + (float)(ws_size >> 6));
    return;
  }

  // ---- ws layout (1,280,512 B) ----
  double* w_d   = (double*)d_ws;                // 512 f64
  double* P1    = w_d + 512;                    // 576 f64
  float*  Lmat  = (float*)(P1 + 576);           // 512*12 f32
  float*  h_all = Lmat + 6144;                  // 294912 f32
  float*  x0T   = h_all + 294912;               // 16384 f32
  int*    curbuf= (int*)(x0T + 16384);          // 512 int

  // ---- big scratch in d_out tail (dead before out_all writes) ----
  char* outb = (char*)d_out;
  float* gi  = (float*)(outb + 50331648);       // [3][1536][64] f32 = 1,179,648 B
  float* hT  = gi + 294912;                     // [3][512][64]  f32 =   393,216 B

  prep<<<dim3(72), dim3(256), 0, stream>>>(x, x0T, Wl, w_d);

  // GRU stack (f32)
  gemm_gates<256><<<dim3(288), dim3(256), 0, stream>>>(Wih0, (long)G3H*IW, bih0, G3H, x0T, 0, gi);
  gru_f<<<dim3(384), dim3(256), 0, stream>>>(gi, bhh0, G3H, h_all, hT, 0);
  gemm_gates<512><<<dim3(288), dim3(256), 0, stream>>>(WihL, (long)2*G3H*HH, bihL, 2*G3H, hT, HH*BB, gi);
  gru_f<<<dim3(384), dim3(256), 0, stream>>>(gi, bhhL, 2*G3H, h_all, hT, 1);
  gemm_gates<512><<<dim3(288), dim3(256), 0, stream>>>(WihL + (size_t)G3H*HH, (long)2*G3H*HH, bihL + G3H, 2*G3H, hT, HH*BB, gi);
  gru_f<<<dim3(384), dim3(256), 0, stream>>>(gi, bhhL + G3H, 2*G3H, h_all, hT, 2);

  dots_fold<<<dim3(3),   dim3(192), 0, stream>>>(h_all, w_d, Ws, bs, P1);
  sums_x   <<<dim3(512), dim3(192), 0, stream>>>(x, Ws, P1, Lmat);

  scan4<<<dim3(1), dim3(64), 0, stream>>>(Lmat, curbuf);

  out_all<<<dim3(608), dim3(256), 0, stream>>>(h_all, curbuf, out);
}